// Round 7
// baseline (492.482 us; speedup 1.0000x reference)
//
#include <hip/hip_runtime.h>
#include <math.h>

#define NN 2048
#define HH 64

typedef _Float16 half8 __attribute__((ext_vector_type(8)));
typedef _Float16 half2_t __attribute__((ext_vector_type(2)));
typedef float f32x4 __attribute__((ext_vector_type(4)));

#define SH (1.0f / 256.0f)
#define INV_SH 256.0f
#define BPAD 132  // f32 row stride: start-bank spread, throughput-min access

#if defined(__has_builtin)
#if __has_builtin(__builtin_amdgcn_cvt_pkrtz)
#define PKRTZ(a, b) ((half2_t)__builtin_amdgcn_cvt_pkrtz((a), (b)))
#endif
#endif
#ifndef PKRTZ
#define PKRTZ(a, b) ((half2_t){(_Float16)(a), (_Float16)(b)})
#endif

union H8u { half2_t h2[4]; half8 h8; };

// ---------- layer 0: x0 = relu((adj @ nf) @ W0 + b0), nf is (N,4) ----------
__global__ __launch_bounds__(256) void gcn0_kernel(const float* __restrict__ adj,
                                                   const float* __restrict__ nf,
                                                   const float* __restrict__ W0,
                                                   const float* __restrict__ b0,
                                                   float* __restrict__ xout) {
  int w = threadIdx.x >> 6;
  int l = threadIdx.x & 63;
  int i = blockIdx.x * 4 + w;
  const float* arow = adj + (size_t)i * NN;
  double s0 = 0, s1 = 0, s2 = 0, s3 = 0;
  for (int k = l; k < NN; k += 64) {
    float a = arow[k];
    float4 v = *(const float4*)(nf + (size_t)k * 4);
    s0 += (double)a * (double)v.x;
    s1 += (double)a * (double)v.y;
    s2 += (double)a * (double)v.z;
    s3 += (double)a * (double)v.w;
  }
  #pragma unroll
  for (int m = 32; m >= 1; m >>= 1) {
    s0 += __shfl_xor(s0, m, 64);
    s1 += __shfl_xor(s1, m, 64);
    s2 += __shfl_xor(s2, m, 64);
    s3 += __shfl_xor(s3, m, 64);
  }
  double y = (double)b0[l];
  y += s0 * (double)W0[0 * HH + l];
  y += s1 * (double)W0[1 * HH + l];
  y += s2 * (double)W0[2 * HH + l];
  y += s3 * (double)W0[3 * HH + l];
  float r = (float)y;
  xout[(size_t)i * HH + l] = r > 0.f ? r : 0.f;
}

// ---------- layers 1,2: xout = relu((adj @ xin) @ W + b); layer2 fuses A/B ----------
#define KT 128
__global__ __launch_bounds__(256) void gcnL_kernel(const float* __restrict__ adj,
                                                   const float* __restrict__ xin,
                                                   const float* __restrict__ W,
                                                   const float* __restrict__ b,
                                                   float* __restrict__ xout,
                                                   const float* __restrict__ We1,
                                                   const float* __restrict__ be1,
                                                   float* __restrict__ Aout,
                                                   float* __restrict__ Bout) {
  __shared__ float xs[KT][HH];
  __shared__ float adjs[4][KT];
  __shared__ double sred[4][HH];
  __shared__ float xr2[4][HH];
  int tid = threadIdx.x;
  int w = tid >> 6, l = tid & 63;
  int i0 = blockIdx.x * 4;
  // 4 independent f64 chains (serial f64 FMA latency was the round-6 gcnL cost)
  double a0 = 0.0, a1 = 0.0, a2 = 0.0, a3 = 0.0;
  for (int k0 = 0; k0 < NN; k0 += KT) {
    __syncthreads();
    const float4* xsrc = (const float4*)(xin + (size_t)k0 * HH);
    float4* xdst = (float4*)&xs[0][0];
    for (int idx = tid; idx < KT * HH / 4; idx += 256) xdst[idx] = xsrc[idx];
    for (int idx = tid; idx < 4 * KT / 4; idx += 256) {
      int r = idx >> 5, c4 = idx & 31;
      *(float4*)&adjs[r][c4 * 4] =
          *(const float4*)(adj + (size_t)(i0 + r) * NN + k0 + c4 * 4);
    }
    __syncthreads();
    #pragma unroll 8
    for (int kk = 0; kk < KT; kk += 4) {
      a0 += (double)adjs[w][kk + 0] * (double)xs[kk + 0][l];
      a1 += (double)adjs[w][kk + 1] * (double)xs[kk + 1][l];
      a2 += (double)adjs[w][kk + 2] * (double)xs[kk + 2][l];
      a3 += (double)adjs[w][kk + 3] * (double)xs[kk + 3][l];
    }
  }
  sred[w][l] = (a0 + a1) + (a2 + a3);
  __syncthreads();
  double y = (double)b[l];
  #pragma unroll 8
  for (int d = 0; d < HH; ++d) y += sred[w][d] * (double)W[d * HH + l];
  float r = (float)y;
  float rres = r > 0.f ? r : 0.f;
  xout[(size_t)(i0 + w) * HH + l] = rres;
  if (Aout != nullptr) {
    // fused edge-MLP layer-1 projection: A = (x2@We1_top + be1)*SH, B = x2@We1_bot*SH
    xr2[w][l] = rres;
    __syncthreads();
    #pragma unroll
    for (int t = 0; t < 2; ++t) {
      int idx = tid + t * 256;         // 0..511
      int rr = idx >> 7, c = idx & 127;
      const float* xr = xr2[rr];
      float accA = be1[c], accB = 0.f;
      #pragma unroll 8
      for (int d = 0; d < HH; ++d) {
        float xv = xr[d];
        accA = fmaf(xv, We1[d * 128 + c], accA);
        accB = fmaf(xv, We1[(HH + d) * 128 + c], accB);
      }
      Aout[(size_t)(i0 + rr) * 128 + c] = accA * SH;
      Bout[(size_t)(i0 + rr) * 128 + c] = accB * SH;
    }
  }
}

// ---------- one-shot We2 split: Wh/Wl f16 [c2][k] row-major ----------
__global__ __launch_bounds__(256) void wsplit_kernel(const float* __restrict__ We2,
                                                     _Float16* __restrict__ Whg,
                                                     _Float16* __restrict__ Wlg) {
  int idx = blockIdx.x * 256 + threadIdx.x;   // 0..8191
  int k = idx >> 6, c2 = idx & 63;
  float wv = We2[idx];
  _Float16 hi = (_Float16)wv;
  float lo = wv - (float)hi;
  Whg[c2 * 128 + k] = hi;
  Wlg[c2 * 128 + k] = (_Float16)lo;
}

// ---------- pair MLP via MFMA (split-f16), 16i x 64j tile, 4 waves ----------
// v3: W fragments read DIRECTLY from global (Whg/Wlg = 32 KB, L1-resident) so
// LDS = As+Bs only (~43 KB) -> 3 blocks/CU (12 waves) instead of 1 block.
// One i-row per pass (4 passes, unroll 1) keeps VGPR ~145 < 168 (3 waves/SIMD).
__global__ __launch_bounds__(256, 3) void pair_kernel(const float* __restrict__ A,
                                                      const float* __restrict__ B,
                                                      const _Float16* __restrict__ Whg,
                                                      const _Float16* __restrict__ Wlg,
                                                      const float* __restrict__ be2,
                                                      const float* __restrict__ We3,
                                                      const float* __restrict__ be3,
                                                      float* __restrict__ out) {
  int j0 = blockIdx.x * 64;
  int i0 = blockIdx.y * 16;
  if (i0 >= j0 + 63) return;         // no pair (i<j) in tile
  __shared__ float As[16][128];      // 8 KB  (reads are quarter-broadcast: no pad)
  __shared__ float Bs[64][BPAD];     // 33.8 KB
  __shared__ float be2s[64];
  __shared__ float We3s[64];
  int tid = threadIdx.x;
  #pragma unroll
  for (int t = 0; t < 2; ++t) {
    int idx = tid + t * 256;         // 0..511
    int r = idx >> 5, c4 = idx & 31;
    *(float4*)&As[r][c4 * 4] = *(const float4*)(A + (size_t)(i0 + r) * 128 + c4 * 4);
  }
  #pragma unroll
  for (int t = 0; t < 8; ++t) {
    int idx = tid + t * 256;         // 0..2047
    int r = idx >> 5, c4 = idx & 31;
    *(float4*)&Bs[r][c4 * 4] = *(const float4*)(B + (size_t)(j0 + r) * 128 + c4 * 4);
  }
  if (tid < 64) { be2s[tid] = be2[tid]; We3s[tid] = We3[tid]; }
  __syncthreads();

  int w = tid >> 6, l = tid & 63;
  int r = l & 15, g = l >> 4;
  float be3v = be3[0];
  float w3[4], sb[4];
  #pragma unroll
  for (int nt = 0; nt < 4; ++nt) {
    w3[nt] = We3s[nt * 16 + r];
    sb[nt] = SH * be2s[nt * 16 + r];
  }
  // W fragment pointers: row (c2) has 16 half8 chunks; chunk = ks*4 + g
  const half8* Whp = (const half8*)Whg;
  const half8* Wlp = (const half8*)Wlg;

  #pragma unroll 1
  for (int ir4 = 0; ir4 < 4; ++ir4) {
    int ir = w * 4 + ir4;            // wave-uniform
    int i = i0 + ir;
    if (i >= j0 + 63) continue;      // no j in this tile exceeds i
    f32x4 acc[4][4];
    #pragma unroll
    for (int js = 0; js < 4; ++js) {
      #pragma unroll
      for (int nt = 0; nt < 4; ++nt) {
        acc[js][nt][0] = sb[nt]; acc[js][nt][1] = sb[nt];
        acc[js][nt][2] = sb[nt]; acc[js][nt][3] = sb[nt];
      }
    }
    #pragma unroll
    for (int ks = 0; ks < 4; ++ks) {
      int kb = ks * 32 + 8 * g;
      half8 wh[4], wl[4];
      #pragma unroll
      for (int nt = 0; nt < 4; ++nt) {
        int row = nt * 16 + r;
        wh[nt] = Whp[row * 16 + ks * 4 + g];
        wl[nt] = Wlp[row * 16 + ks * 4 + g];
      }
      float4 a0 = *(const float4*)&As[ir][kb];
      float4 a1 = *(const float4*)&As[ir][kb + 4];
      #pragma unroll
      for (int js = 0; js < 4; ++js) {
        float4 b0 = *(const float4*)&Bs[js * 16 + r][kb];
        float4 b1 = *(const float4*)&Bs[js * 16 + r][kb + 4];
        float s0 = fmaxf(a0.x + b0.x, 0.f);
        float s1 = fmaxf(a0.y + b0.y, 0.f);
        float s2 = fmaxf(a0.z + b0.z, 0.f);
        float s3 = fmaxf(a0.w + b0.w, 0.f);
        float s4 = fmaxf(a1.x + b1.x, 0.f);
        float s5 = fmaxf(a1.y + b1.y, 0.f);
        float s6 = fmaxf(a1.z + b1.z, 0.f);
        float s7 = fmaxf(a1.w + b1.w, 0.f);
        H8u hh, hl;
        hh.h2[0] = PKRTZ(s0, s1);
        hh.h2[1] = PKRTZ(s2, s3);
        hh.h2[2] = PKRTZ(s4, s5);
        hh.h2[3] = PKRTZ(s6, s7);
        hl.h2[0] = PKRTZ(s0 - (float)hh.h2[0][0], s1 - (float)hh.h2[0][1]);
        hl.h2[1] = PKRTZ(s2 - (float)hh.h2[1][0], s3 - (float)hh.h2[1][1]);
        hl.h2[2] = PKRTZ(s4 - (float)hh.h2[2][0], s5 - (float)hh.h2[2][1]);
        hl.h2[3] = PKRTZ(s6 - (float)hh.h2[3][0], s7 - (float)hh.h2[3][1]);
        #pragma unroll
        for (int nt = 0; nt < 4; ++nt) {
          acc[js][nt] = __builtin_amdgcn_mfma_f32_16x16x32_f16(hh.h8, wh[nt], acc[js][nt], 0, 0, 0);
          acc[js][nt] = __builtin_amdgcn_mfma_f32_16x16x32_f16(hh.h8, wl[nt], acc[js][nt], 0, 0, 0);
          acc[js][nt] = __builtin_amdgcn_mfma_f32_16x16x32_f16(hl.h8, wh[nt], acc[js][nt], 0, 0, 0);
        }
      }
    }
    // epilogue: h2 = relu(acc)/SH; logit = sum h2*We3 + be3
    #pragma unroll
    for (int js = 0; js < 4; ++js) {
      float p0 = 0.f, p1 = 0.f, p2 = 0.f, p3 = 0.f;
      #pragma unroll
      for (int nt = 0; nt < 4; ++nt) {
        f32x4 v = acc[js][nt];
        p0 += fmaxf(v[0], 0.f) * w3[nt];
        p1 += fmaxf(v[1], 0.f) * w3[nt];
        p2 += fmaxf(v[2], 0.f) * w3[nt];
        p3 += fmaxf(v[3], 0.f) * w3[nt];
      }
      #pragma unroll
      for (int m = 1; m <= 8; m <<= 1) {
        p0 += __shfl_xor(p0, m, 64);
        p1 += __shfl_xor(p1, m, 64);
        p2 += __shfl_xor(p2, m, 64);
        p3 += __shfl_xor(p3, m, 64);
      }
      if (r == 0) {
        int jb2 = j0 + js * 16 + 4 * g;
        int j;
        float logit;
        j = jb2 + 0;
        if (j > i) {
          logit = p0 * INV_SH + be3v;
          out[i * (NN - 1) - (i * (i - 1)) / 2 + (j - i - 1)] =
              1.0f / (1.0f + expf(-logit));
        }
        j = jb2 + 1;
        if (j > i) {
          logit = p1 * INV_SH + be3v;
          out[i * (NN - 1) - (i * (i - 1)) / 2 + (j - i - 1)] =
              1.0f / (1.0f + expf(-logit));
        }
        j = jb2 + 2;
        if (j > i) {
          logit = p2 * INV_SH + be3v;
          out[i * (NN - 1) - (i * (i - 1)) / 2 + (j - i - 1)] =
              1.0f / (1.0f + expf(-logit));
        }
        j = jb2 + 3;
        if (j > i) {
          logit = p3 * INV_SH + be3v;
          out[i * (NN - 1) - (i * (i - 1)) / 2 + (j - i - 1)] =
              1.0f / (1.0f + expf(-logit));
        }
      }
    }
  }
}

extern "C" void kernel_launch(void* const* d_in, const int* in_sizes, int n_in,
                              void* d_out, int out_size, void* d_ws, size_t ws_size,
                              hipStream_t stream) {
  (void)in_sizes; (void)n_in; (void)out_size; (void)ws_size;
  const float* nf  = (const float*)d_in[0];
  const float* adj = (const float*)d_in[1];
  const float* W0  = (const float*)d_in[2];
  const float* b0  = (const float*)d_in[3];
  const float* W1  = (const float*)d_in[4];
  const float* b1  = (const float*)d_in[5];
  const float* W2  = (const float*)d_in[6];
  const float* b2  = (const float*)d_in[7];
  const float* We1 = (const float*)d_in[8];
  const float* be1 = (const float*)d_in[9];
  const float* We2 = (const float*)d_in[10];
  const float* be2 = (const float*)d_in[11];
  const float* We3 = (const float*)d_in[12];
  const float* be3 = (const float*)d_in[13];
  float* out = (float*)d_out;

  // Workspace layout (max 3584 KB):
  //  [0,512K):    x0, later overwritten by x2 (x0 dead after layer 1)
  //  [512K,1024K): x1
  //  [1024K,1040K): Whg ; [1040K,1056K): Wlg
  //  [1536K,2560K): Ab ; [2560K,3584K): Bb
  char* ws = (char*)d_ws;
  float* x0 = (float*)(ws);
  float* x1 = (float*)(ws + (512 << 10));
  float* x2 = (float*)(ws);                        // reuse x0 slot
  _Float16* Whg = (_Float16*)(ws + (1024 << 10));  // 16 KB
  _Float16* Wlg = (_Float16*)(ws + (1040 << 10));  // 16 KB
  float* Ab = (float*)(ws + (1536 << 10));         // 1 MB (pre-scaled)
  float* Bb = (float*)(ws + (2560 << 10));         // 1 MB (pre-scaled)

  wsplit_kernel<<<32, 256, 0, stream>>>(We2, Whg, Wlg);
  gcn0_kernel<<<NN / 4, 256, 0, stream>>>(adj, nf, W0, b0, x0);
  gcnL_kernel<<<NN / 4, 256, 0, stream>>>(adj, x0, W1, b1, x1,
                                          nullptr, nullptr, nullptr, nullptr);
  gcnL_kernel<<<NN / 4, 256, 0, stream>>>(adj, x1, W2, b2, x2,
                                          We1, be1, Ab, Bb);
  pair_kernel<<<dim3(NN / 64, NN / 16), 256, 0, stream>>>(Ab, Bb, Whg, Wlg,
                                                          be2, We3, be3, out);
}

// Round 9
// 430.351 us; speedup vs baseline: 1.1444x; 1.1444x over previous
//
#include <hip/hip_runtime.h>
#include <math.h>

#define NN 2048
#define HH 64

typedef _Float16 half8 __attribute__((ext_vector_type(8)));
typedef _Float16 half2_t __attribute__((ext_vector_type(2)));
typedef float f32x4 __attribute__((ext_vector_type(4)));

#define SH (1.0f / 256.0f)
#define INV_SH 256.0f
#define BPAD 132  // f32 row stride: start-bank spread
#define SMEM_FLOATS (16 * 128 + 64 * BPAD)  // As(8KB) + Bs(33.8KB); W stage fits inside

#if defined(__has_builtin)
#if __has_builtin(__builtin_amdgcn_cvt_pkrtz)
#define PKRTZ(a, b) ((half2_t)__builtin_amdgcn_cvt_pkrtz((a), (b)))
#endif
#endif
#ifndef PKRTZ
#define PKRTZ(a, b) ((half2_t){(_Float16)(a), (_Float16)(b)})
#endif

union H8u { half2_t h2[4]; half8 h8; };

// ---------- layer 0: x0 = relu((adj @ nf) @ W0 + b0), nf is (N,4) ----------
__global__ __launch_bounds__(256) void gcn0_kernel(const float* __restrict__ adj,
                                                   const float* __restrict__ nf,
                                                   const float* __restrict__ W0,
                                                   const float* __restrict__ b0,
                                                   float* __restrict__ xout) {
  int w = threadIdx.x >> 6;
  int l = threadIdx.x & 63;
  int i = blockIdx.x * 4 + w;
  const float* arow = adj + (size_t)i * NN;
  double s0 = 0, s1 = 0, s2 = 0, s3 = 0;
  for (int k = l; k < NN; k += 64) {
    float a = arow[k];
    float4 v = *(const float4*)(nf + (size_t)k * 4);
    s0 += (double)a * (double)v.x;
    s1 += (double)a * (double)v.y;
    s2 += (double)a * (double)v.z;
    s3 += (double)a * (double)v.w;
  }
  #pragma unroll
  for (int m = 32; m >= 1; m >>= 1) {
    s0 += __shfl_xor(s0, m, 64);
    s1 += __shfl_xor(s1, m, 64);
    s2 += __shfl_xor(s2, m, 64);
    s3 += __shfl_xor(s3, m, 64);
  }
  double y = (double)b0[l];
  y += s0 * (double)W0[0 * HH + l];
  y += s1 * (double)W0[1 * HH + l];
  y += s2 * (double)W0[2 * HH + l];
  y += s3 * (double)W0[3 * HH + l];
  float r = (float)y;
  xout[(size_t)i * HH + l] = r > 0.f ? r : 0.f;
}

// ---------- layers 1,2: xout = relu((adj @ xin) @ W + b); layer2 fuses A/B ----------
#define KT 128
__global__ __launch_bounds__(256) void gcnL_kernel(const float* __restrict__ adj,
                                                   const float* __restrict__ xin,
                                                   const float* __restrict__ W,
                                                   const float* __restrict__ b,
                                                   float* __restrict__ xout,
                                                   const float* __restrict__ We1,
                                                   const float* __restrict__ be1,
                                                   float* __restrict__ Aout,
                                                   float* __restrict__ Bout) {
  __shared__ float xs[KT][HH];
  __shared__ float adjs[4][KT];
  __shared__ double sred[4][HH];
  __shared__ float xr2[4][HH];
  int tid = threadIdx.x;
  int w = tid >> 6, l = tid & 63;
  int i0 = blockIdx.x * 4;
  double a0 = 0.0, a1 = 0.0, a2 = 0.0, a3 = 0.0;
  for (int k0 = 0; k0 < NN; k0 += KT) {
    __syncthreads();
    const float4* xsrc = (const float4*)(xin + (size_t)k0 * HH);
    float4* xdst = (float4*)&xs[0][0];
    for (int idx = tid; idx < KT * HH / 4; idx += 256) xdst[idx] = xsrc[idx];
    for (int idx = tid; idx < 4 * KT / 4; idx += 256) {
      int r = idx >> 5, c4 = idx & 31;
      *(float4*)&adjs[r][c4 * 4] =
          *(const float4*)(adj + (size_t)(i0 + r) * NN + k0 + c4 * 4);
    }
    __syncthreads();
    #pragma unroll 8
    for (int kk = 0; kk < KT; kk += 4) {
      a0 += (double)adjs[w][kk + 0] * (double)xs[kk + 0][l];
      a1 += (double)adjs[w][kk + 1] * (double)xs[kk + 1][l];
      a2 += (double)adjs[w][kk + 2] * (double)xs[kk + 2][l];
      a3 += (double)adjs[w][kk + 3] * (double)xs[kk + 3][l];
    }
  }
  sred[w][l] = (a0 + a1) + (a2 + a3);
  __syncthreads();
  double y = (double)b[l];
  #pragma unroll 8
  for (int d = 0; d < HH; ++d) y += sred[w][d] * (double)W[d * HH + l];
  float r = (float)y;
  float rres = r > 0.f ? r : 0.f;
  xout[(size_t)(i0 + w) * HH + l] = rres;
  if (Aout != nullptr) {
    xr2[w][l] = rres;
    __syncthreads();
    #pragma unroll
    for (int t = 0; t < 2; ++t) {
      int idx = tid + t * 256;         // 0..511
      int rr = idx >> 7, c = idx & 127;
      const float* xr = xr2[rr];
      float accA = be1[c], accB = 0.f;
      #pragma unroll 8
      for (int d = 0; d < HH; ++d) {
        float xv = xr[d];
        accA = fmaf(xv, We1[d * 128 + c], accA);
        accB = fmaf(xv, We1[(HH + d) * 128 + c], accB);
      }
      Aout[(size_t)(i0 + rr) * 128 + c] = accA * SH;
      Bout[(size_t)(i0 + rr) * 128 + c] = accB * SH;
    }
  }
}

// ---------- one-shot We2 split: Wh/Wl f16 [c2][k] row-major ----------
__global__ __launch_bounds__(256) void wsplit_kernel(const float* __restrict__ We2,
                                                     _Float16* __restrict__ Whg,
                                                     _Float16* __restrict__ Wlg) {
  int idx = blockIdx.x * 256 + threadIdx.x;   // 0..8191
  int k = idx >> 6, c2 = idx & 63;
  float wv = We2[idx];
  _Float16 hi = (_Float16)wv;
  float lo = wv - (float)hi;
  Whg[c2 * 128 + k] = hi;
  Wlg[c2 * 128 + k] = (_Float16)lo;
}

// ---------- pair MLP via MFMA (split-f16), 16i x 64j tile, 4 waves ----------
// v4b: W fragments live in REGISTERS (loaded once via transient LDS stage that
// is then overwritten by As/Bs -> LDS stays ~42.3 KB). Main loop touches only
// As/Bs LDS + VALU h-split + MFMA. 2 waves/SIMD via __launch_bounds__(256,2).
// ROUND-8 BUG FIXED: W-stage swizzle must XOR with (row & 15) — the read side
// unswizzles with r = row&15; XORing the full 6-bit row scrambled rows 16..63.
__global__ __launch_bounds__(256, 2) void pair_kernel(const float* __restrict__ A,
                                                      const float* __restrict__ B,
                                                      const _Float16* __restrict__ Whg,
                                                      const _Float16* __restrict__ Wlg,
                                                      const float* __restrict__ be2,
                                                      const float* __restrict__ We3,
                                                      const float* __restrict__ be3,
                                                      float* __restrict__ out) {
  int j0 = blockIdx.x * 64;
  int i0 = blockIdx.y * 16;
  if (i0 >= j0 + 63) return;         // no pair (i<j) in tile
  __shared__ __align__(16) float smem[SMEM_FLOATS];  // 42 KB union
  __shared__ float be2s[64];
  __shared__ float We3s[64];
  int tid = threadIdx.x;
  int w = tid >> 6, l = tid & 63;
  int r = l & 15, g = l >> 4;

  // ---- phase 1: stage Wh/Wl (chunk-XOR swizzle), pull fragments to regs ----
  {
    half8* Wst = (half8*)smem;       // 2048 chunks = 32 KB, fits in union
    #pragma unroll
    for (int t = 0; t < 8; ++t) {
      int idx = tid + t * 256;       // 0..2047; coalesced global 16B/lane
      int arr = idx >> 10;           // 0 = Wh, 1 = Wl
      int c = idx & 1023;
      int row = c >> 4, ch = c & 15;
      const half8* src = arr ? (const half8*)Wlg : (const half8*)Whg;
      Wst[arr * 1024 + row * 16 + (ch ^ (row & 15))] = src[c];  // FIXED: & 15
    }
  }
  if (tid < 64) { be2s[tid] = be2[tid]; We3s[tid] = We3[tid]; }
  __syncthreads();
  half8 wh[4][4], wl[4][4];
  {
    const half8* Wst = (const half8*)smem;
    #pragma unroll
    for (int nt = 0; nt < 4; ++nt) {
      #pragma unroll
      for (int ks = 0; ks < 4; ++ks) {
        int a = (nt * 16 + r) * 16 + ((ks * 4 + g) ^ r);
        wh[nt][ks] = Wst[a];
        wl[nt][ks] = Wst[1024 + a];
      }
    }
  }
  __syncthreads();                   // W regs secured; free the LDS region

  // ---- phase 2: stage As/Bs over the same LDS ----
  float (*As)[128] = (float(*)[128])smem;                   // 8 KB
  float (*Bs)[BPAD] = (float(*)[BPAD])(smem + 16 * 128);    // 33.8 KB
  #pragma unroll
  for (int t = 0; t < 2; ++t) {
    int idx = tid + t * 256;         // 0..511
    int rr = idx >> 5, c4 = idx & 31;
    *(float4*)&As[rr][c4 * 4] = *(const float4*)(A + (size_t)(i0 + rr) * 128 + c4 * 4);
  }
  #pragma unroll
  for (int t = 0; t < 8; ++t) {
    int idx = tid + t * 256;         // 0..2047
    int rr = idx >> 5, c4 = idx & 31;
    *(float4*)&Bs[rr][c4 * 4] = *(const float4*)(B + (size_t)(j0 + rr) * 128 + c4 * 4);
  }
  __syncthreads();

  float be3v = be3[0];
  float w3[4], sb[4];
  #pragma unroll
  for (int nt = 0; nt < 4; ++nt) {
    w3[nt] = We3s[nt * 16 + r];
    sb[nt] = SH * be2s[nt * 16 + r];
  }

  #pragma unroll 1
  for (int ir4 = 0; ir4 < 4; ++ir4) {
    int ir = w * 4 + ir4;            // wave-uniform
    int i = i0 + ir;
    if (i >= j0 + 63) continue;
    f32x4 acc[4][4];
    #pragma unroll
    for (int js = 0; js < 4; ++js) {
      #pragma unroll
      for (int nt = 0; nt < 4; ++nt) {
        acc[js][nt][0] = sb[nt]; acc[js][nt][1] = sb[nt];
        acc[js][nt][2] = sb[nt]; acc[js][nt][3] = sb[nt];
      }
    }
    #pragma unroll
    for (int ks = 0; ks < 4; ++ks) {
      int kb = ks * 32 + 8 * g;
      float4 a0 = *(const float4*)&As[ir][kb];
      float4 a1 = *(const float4*)&As[ir][kb + 4];
      #pragma unroll
      for (int js = 0; js < 4; ++js) {
        float4 b0 = *(const float4*)&Bs[js * 16 + r][kb];
        float4 b1 = *(const float4*)&Bs[js * 16 + r][kb + 4];
        float s0 = fmaxf(a0.x + b0.x, 0.f);
        float s1 = fmaxf(a0.y + b0.y, 0.f);
        float s2 = fmaxf(a0.z + b0.z, 0.f);
        float s3 = fmaxf(a0.w + b0.w, 0.f);
        float s4 = fmaxf(a1.x + b1.x, 0.f);
        float s5 = fmaxf(a1.y + b1.y, 0.f);
        float s6 = fmaxf(a1.z + b1.z, 0.f);
        float s7 = fmaxf(a1.w + b1.w, 0.f);
        H8u hh, hl;
        hh.h2[0] = PKRTZ(s0, s1);
        hh.h2[1] = PKRTZ(s2, s3);
        hh.h2[2] = PKRTZ(s4, s5);
        hh.h2[3] = PKRTZ(s6, s7);
        hl.h2[0] = PKRTZ(s0 - (float)hh.h2[0][0], s1 - (float)hh.h2[0][1]);
        hl.h2[1] = PKRTZ(s2 - (float)hh.h2[1][0], s3 - (float)hh.h2[1][1]);
        hl.h2[2] = PKRTZ(s4 - (float)hh.h2[2][0], s5 - (float)hh.h2[2][1]);
        hl.h2[3] = PKRTZ(s6 - (float)hh.h2[3][0], s7 - (float)hh.h2[3][1]);
        #pragma unroll
        for (int nt = 0; nt < 4; ++nt) {
          acc[js][nt] = __builtin_amdgcn_mfma_f32_16x16x32_f16(hh.h8, wh[nt][ks], acc[js][nt], 0, 0, 0);
          acc[js][nt] = __builtin_amdgcn_mfma_f32_16x16x32_f16(hh.h8, wl[nt][ks], acc[js][nt], 0, 0, 0);
          acc[js][nt] = __builtin_amdgcn_mfma_f32_16x16x32_f16(hl.h8, wh[nt][ks], acc[js][nt], 0, 0, 0);
        }
      }
    }
    // epilogue: h2 = relu(acc)/SH; logit = sum h2*We3 + be3
    #pragma unroll
    for (int js = 0; js < 4; ++js) {
      float p0 = 0.f, p1 = 0.f, p2 = 0.f, p3 = 0.f;
      #pragma unroll
      for (int nt = 0; nt < 4; ++nt) {
        f32x4 v = acc[js][nt];
        p0 += fmaxf(v[0], 0.f) * w3[nt];
        p1 += fmaxf(v[1], 0.f) * w3[nt];
        p2 += fmaxf(v[2], 0.f) * w3[nt];
        p3 += fmaxf(v[3], 0.f) * w3[nt];
      }
      #pragma unroll
      for (int m = 1; m <= 8; m <<= 1) {
        p0 += __shfl_xor(p0, m, 64);
        p1 += __shfl_xor(p1, m, 64);
        p2 += __shfl_xor(p2, m, 64);
        p3 += __shfl_xor(p3, m, 64);
      }
      if (r == 0) {
        int jb2 = j0 + js * 16 + 4 * g;
        int j;
        float logit;
        j = jb2 + 0;
        if (j > i) {
          logit = p0 * INV_SH + be3v;
          out[i * (NN - 1) - (i * (i - 1)) / 2 + (j - i - 1)] =
              1.0f / (1.0f + expf(-logit));
        }
        j = jb2 + 1;
        if (j > i) {
          logit = p1 * INV_SH + be3v;
          out[i * (NN - 1) - (i * (i - 1)) / 2 + (j - i - 1)] =
              1.0f / (1.0f + expf(-logit));
        }
        j = jb2 + 2;
        if (j > i) {
          logit = p2 * INV_SH + be3v;
          out[i * (NN - 1) - (i * (i - 1)) / 2 + (j - i - 1)] =
              1.0f / (1.0f + expf(-logit));
        }
        j = jb2 + 3;
        if (j > i) {
          logit = p3 * INV_SH + be3v;
          out[i * (NN - 1) - (i * (i - 1)) / 2 + (j - i - 1)] =
              1.0f / (1.0f + expf(-logit));
        }
      }
    }
  }
}

extern "C" void kernel_launch(void* const* d_in, const int* in_sizes, int n_in,
                              void* d_out, int out_size, void* d_ws, size_t ws_size,
                              hipStream_t stream) {
  (void)in_sizes; (void)n_in; (void)out_size; (void)ws_size;
  const float* nf  = (const float*)d_in[0];
  const float* adj = (const float*)d_in[1];
  const float* W0  = (const float*)d_in[2];
  const float* b0  = (const float*)d_in[3];
  const float* W1  = (const float*)d_in[4];
  const float* b1  = (const float*)d_in[5];
  const float* W2  = (const float*)d_in[6];
  const float* b2  = (const float*)d_in[7];
  const float* We1 = (const float*)d_in[8];
  const float* be1 = (const float*)d_in[9];
  const float* We2 = (const float*)d_in[10];
  const float* be2 = (const float*)d_in[11];
  const float* We3 = (const float*)d_in[12];
  const float* be3 = (const float*)d_in[13];
  float* out = (float*)d_out;

  // Workspace layout (max 3584 KB):
  //  [0,512K):    x0, later overwritten by x2 (x0 dead after layer 1)
  //  [512K,1024K): x1
  //  [1024K,1040K): Whg ; [1040K,1056K): Wlg
  //  [1536K,2560K): Ab ; [2560K,3584K): Bb
  char* ws = (char*)d_ws;
  float* x0 = (float*)(ws);
  float* x1 = (float*)(ws + (512 << 10));
  float* x2 = (float*)(ws);                        // reuse x0 slot
  _Float16* Whg = (_Float16*)(ws + (1024 << 10));  // 16 KB
  _Float16* Wlg = (_Float16*)(ws + (1040 << 10));  // 16 KB
  float* Ab = (float*)(ws + (1536 << 10));         // 1 MB (pre-scaled)
  float* Bb = (float*)(ws + (2560 << 10));         // 1 MB (pre-scaled)

  wsplit_kernel<<<32, 256, 0, stream>>>(We2, Whg, Wlg);
  gcn0_kernel<<<NN / 4, 256, 0, stream>>>(adj, nf, W0, b0, x0);
  gcnL_kernel<<<NN / 4, 256, 0, stream>>>(adj, x0, W1, b1, x1,
                                          nullptr, nullptr, nullptr, nullptr);
  gcnL_kernel<<<NN / 4, 256, 0, stream>>>(adj, x1, W2, b2, x2,
                                          We1, be1, Ab, Bb);
  pair_kernel<<<dim3(NN / 64, NN / 16), 256, 0, stream>>>(Ab, Bb, Whg, Wlg,
                                                          be2, We3, be3, out);
}

// Round 10
// 390.652 us; speedup vs baseline: 1.2607x; 1.1016x over previous
//
#include <hip/hip_runtime.h>
#include <math.h>

#define NN 2048
#define HH 64

typedef _Float16 half8 __attribute__((ext_vector_type(8)));
typedef _Float16 half2_t __attribute__((ext_vector_type(2)));
typedef float f32x4 __attribute__((ext_vector_type(4)));

#define SH (1.0f / 256.0f)
#define INV_SH 256.0f
#define BPAD 132  // f32 row stride

#if defined(__has_builtin)
#if __has_builtin(__builtin_amdgcn_cvt_pkrtz)
#define PKRTZ(a, b) ((half2_t)__builtin_amdgcn_cvt_pkrtz((a), (b)))
#endif
#endif
#ifndef PKRTZ
#define PKRTZ(a, b) ((half2_t){(_Float16)(a), (_Float16)(b)})
#endif

union H8u { half2_t h2[4]; half8 h8; };

// ---------- layer 0: x0 = relu((adj @ nf) @ W0 + b0), nf is (N,4) ----------
__global__ __launch_bounds__(256) void gcn0_kernel(const float* __restrict__ adj,
                                                   const float* __restrict__ nf,
                                                   const float* __restrict__ W0,
                                                   const float* __restrict__ b0,
                                                   float* __restrict__ xout) {
  int w = threadIdx.x >> 6;
  int l = threadIdx.x & 63;
  int i = blockIdx.x * 4 + w;
  const float* arow = adj + (size_t)i * NN;
  double s0 = 0, s1 = 0, s2 = 0, s3 = 0;
  for (int k = l; k < NN; k += 64) {
    float a = arow[k];
    float4 v = *(const float4*)(nf + (size_t)k * 4);
    s0 += (double)a * (double)v.x;
    s1 += (double)a * (double)v.y;
    s2 += (double)a * (double)v.z;
    s3 += (double)a * (double)v.w;
  }
  #pragma unroll
  for (int m = 32; m >= 1; m >>= 1) {
    s0 += __shfl_xor(s0, m, 64);
    s1 += __shfl_xor(s1, m, 64);
    s2 += __shfl_xor(s2, m, 64);
    s3 += __shfl_xor(s3, m, 64);
  }
  double y = (double)b0[l];
  y += s0 * (double)W0[0 * HH + l];
  y += s1 * (double)W0[1 * HH + l];
  y += s2 * (double)W0[2 * HH + l];
  y += s3 * (double)W0[3 * HH + l];
  float r = (float)y;
  xout[(size_t)i * HH + l] = r > 0.f ? r : 0.f;
}

// ---------- layers 1,2: xout = relu((adj @ xin) @ W + b); layer2 fuses A/B ----------
#define KT 128
__global__ __launch_bounds__(256) void gcnL_kernel(const float* __restrict__ adj,
                                                   const float* __restrict__ xin,
                                                   const float* __restrict__ W,
                                                   const float* __restrict__ b,
                                                   float* __restrict__ xout,
                                                   const float* __restrict__ We1,
                                                   const float* __restrict__ be1,
                                                   float* __restrict__ Aout,
                                                   float* __restrict__ Bout) {
  __shared__ float xs[KT][HH];
  __shared__ float adjs[4][KT];
  __shared__ double sred[4][HH];
  __shared__ float xr2[4][HH];
  int tid = threadIdx.x;
  int w = tid >> 6, l = tid & 63;
  int i0 = blockIdx.x * 4;
  double a0 = 0.0, a1 = 0.0, a2 = 0.0, a3 = 0.0;
  for (int k0 = 0; k0 < NN; k0 += KT) {
    __syncthreads();
    const float4* xsrc = (const float4*)(xin + (size_t)k0 * HH);
    float4* xdst = (float4*)&xs[0][0];
    for (int idx = tid; idx < KT * HH / 4; idx += 256) xdst[idx] = xsrc[idx];
    for (int idx = tid; idx < 4 * KT / 4; idx += 256) {
      int r = idx >> 5, c4 = idx & 31;
      *(float4*)&adjs[r][c4 * 4] =
          *(const float4*)(adj + (size_t)(i0 + r) * NN + k0 + c4 * 4);
    }
    __syncthreads();
    #pragma unroll 8
    for (int kk = 0; kk < KT; kk += 4) {
      a0 += (double)adjs[w][kk + 0] * (double)xs[kk + 0][l];
      a1 += (double)adjs[w][kk + 1] * (double)xs[kk + 1][l];
      a2 += (double)adjs[w][kk + 2] * (double)xs[kk + 2][l];
      a3 += (double)adjs[w][kk + 3] * (double)xs[kk + 3][l];
    }
  }
  sred[w][l] = (a0 + a1) + (a2 + a3);
  __syncthreads();
  double y = (double)b[l];
  #pragma unroll 8
  for (int d = 0; d < HH; ++d) y += sred[w][d] * (double)W[d * HH + l];
  float r = (float)y;
  float rres = r > 0.f ? r : 0.f;
  xout[(size_t)(i0 + w) * HH + l] = rres;
  if (Aout != nullptr) {
    xr2[w][l] = rres;
    __syncthreads();
    #pragma unroll
    for (int t = 0; t < 2; ++t) {
      int idx = tid + t * 256;         // 0..511
      int rr = idx >> 7, c = idx & 127;
      const float* xr = xr2[rr];
      float accA = be1[c], accB = 0.f;
      #pragma unroll 8
      for (int d = 0; d < HH; ++d) {
        float xv = xr[d];
        accA = fmaf(xv, We1[d * 128 + c], accA);
        accB = fmaf(xv, We1[(HH + d) * 128 + c], accB);
      }
      Aout[(size_t)(i0 + rr) * 128 + c] = accA * SH;
      Bout[(size_t)(i0 + rr) * 128 + c] = accB * SH;
    }
  }
}

// ---------- one-shot We2 split: Wh/Wl f16 [c2][k] row-major ----------
__global__ __launch_bounds__(256) void wsplit_kernel(const float* __restrict__ We2,
                                                     _Float16* __restrict__ Whg,
                                                     _Float16* __restrict__ Wlg) {
  int idx = blockIdx.x * 256 + threadIdx.x;   // 0..8191
  int k = idx >> 6, c2 = idx & 63;
  float wv = We2[idx];
  _Float16 hi = (_Float16)wv;
  float lo = wv - (float)hi;
  Whg[c2 * 128 + k] = hi;
  Wlg[c2 * 128 + k] = (_Float16)lo;
}

// ---------- pair MLP via MFMA (split-f16), 32i x 64j tile, 8 waves ----------
// v5: 512-thread block => 8 waves = 2 waves/SIMD co-resident BY CONSTRUCTION
// (no reliance on multi-block residency). W in LDS (swizzled, proven layout),
// loads hoisted per ks and amortized over 2 i-streams x 4 js = 24 MFMAs.
// LDS = W 32K + As 16K + Bs 33.8K + 0.5K ~ 83 KB (single block per CU).
__global__ __launch_bounds__(512, 1) void pair_kernel(const float* __restrict__ A,
                                                      const float* __restrict__ B,
                                                      const _Float16* __restrict__ Whg,
                                                      const _Float16* __restrict__ Wlg,
                                                      const float* __restrict__ be2,
                                                      const float* __restrict__ We3,
                                                      const float* __restrict__ be3,
                                                      float* __restrict__ out) {
  int j0 = blockIdx.x * 64;
  int i0 = blockIdx.y * 32;
  if (i0 >= j0 + 63) return;         // no pair (i<j) in tile
  __shared__ __align__(16) _Float16 Wst8[2048 * 8];  // 32 KB, [Wh|Wl] swizzled
  __shared__ float As[32][128];      // 16 KB (reads quarter-broadcast)
  __shared__ float Bs[64][BPAD];     // 33.8 KB
  __shared__ float be2s[64];
  __shared__ float We3s[64];
  int tid = threadIdx.x;
  int w = tid >> 6, l = tid & 63;
  int r = l & 15, g = l >> 4;

  {
    half8* Wst = (half8*)Wst8;
    #pragma unroll
    for (int t = 0; t < 4; ++t) {
      int idx = tid + t * 512;       // 0..2047
      int arr = idx >> 10;           // 0 = Wh, 1 = Wl
      int c = idx & 1023;
      int row = c >> 4, ch = c & 15;
      const half8* src = arr ? (const half8*)Wlg : (const half8*)Whg;
      Wst[arr * 1024 + row * 16 + (ch ^ (row & 15))] = src[c];
    }
  }
  #pragma unroll
  for (int t = 0; t < 2; ++t) {
    int idx = tid + t * 512;         // 0..1023
    int rr = idx >> 5, c4 = idx & 31;
    *(float4*)&As[rr][c4 * 4] = *(const float4*)(A + (size_t)(i0 + rr) * 128 + c4 * 4);
  }
  #pragma unroll
  for (int t = 0; t < 4; ++t) {
    int idx = tid + t * 512;         // 0..2047
    int rr = idx >> 5, c4 = idx & 31;
    *(float4*)&Bs[rr][c4 * 4] = *(const float4*)(B + (size_t)(j0 + rr) * 128 + c4 * 4);
  }
  if (tid < 64) { be2s[tid] = be2[tid]; We3s[tid] = We3[tid]; }
  __syncthreads();

  const half8* Wst = (const half8*)Wst8;
  float be3v = be3[0];
  float w3[4], sb[4];
  #pragma unroll
  for (int nt = 0; nt < 4; ++nt) {
    w3[nt] = We3s[nt * 16 + r];
    sb[nt] = SH * be2s[nt * 16 + r];
  }

  #pragma unroll 1
  for (int ip = 0; ip < 2; ++ip) {
    int irA = w * 4 + ip * 2;
    int irB = irA + 1;
    int iA = i0 + irA, iB = i0 + irB;
    if (iA >= j0 + 63) continue;     // no valid j for iA (nor iB > iA)
    f32x4 accA[4][4], accB[4][4];
    #pragma unroll
    for (int js = 0; js < 4; ++js) {
      #pragma unroll
      for (int nt = 0; nt < 4; ++nt) {
        accA[js][nt][0] = sb[nt]; accA[js][nt][1] = sb[nt];
        accA[js][nt][2] = sb[nt]; accA[js][nt][3] = sb[nt];
        accB[js][nt][0] = sb[nt]; accB[js][nt][1] = sb[nt];
        accB[js][nt][2] = sb[nt]; accB[js][nt][3] = sb[nt];
      }
    }
    #pragma unroll
    for (int ks = 0; ks < 4; ++ks) {
      int kb = ks * 32 + 8 * g;
      half8 wh[4], wl[4];
      #pragma unroll
      for (int nt = 0; nt < 4; ++nt) {
        int a = (nt * 16 + r) * 16 + ((ks * 4 + g) ^ r);
        wh[nt] = Wst[a];
        wl[nt] = Wst[1024 + a];
      }
      float4 aA0 = *(const float4*)&As[irA][kb];
      float4 aA1 = *(const float4*)&As[irA][kb + 4];
      float4 aB0 = *(const float4*)&As[irB][kb];
      float4 aB1 = *(const float4*)&As[irB][kb + 4];
      #pragma unroll
      for (int js = 0; js < 4; ++js) {
        float4 b0 = *(const float4*)&Bs[js * 16 + r][kb];
        float4 b1 = *(const float4*)&Bs[js * 16 + r][kb + 4];
        // stream A
        float sA0 = fmaxf(aA0.x + b0.x, 0.f);
        float sA1 = fmaxf(aA0.y + b0.y, 0.f);
        float sA2 = fmaxf(aA0.z + b0.z, 0.f);
        float sA3 = fmaxf(aA0.w + b0.w, 0.f);
        float sA4 = fmaxf(aA1.x + b1.x, 0.f);
        float sA5 = fmaxf(aA1.y + b1.y, 0.f);
        float sA6 = fmaxf(aA1.z + b1.z, 0.f);
        float sA7 = fmaxf(aA1.w + b1.w, 0.f);
        H8u hhA, hlA;
        hhA.h2[0] = PKRTZ(sA0, sA1);
        hhA.h2[1] = PKRTZ(sA2, sA3);
        hhA.h2[2] = PKRTZ(sA4, sA5);
        hhA.h2[3] = PKRTZ(sA6, sA7);
        hlA.h2[0] = PKRTZ(sA0 - (float)hhA.h2[0][0], sA1 - (float)hhA.h2[0][1]);
        hlA.h2[1] = PKRTZ(sA2 - (float)hhA.h2[1][0], sA3 - (float)hhA.h2[1][1]);
        hlA.h2[2] = PKRTZ(sA4 - (float)hhA.h2[2][0], sA5 - (float)hhA.h2[2][1]);
        hlA.h2[3] = PKRTZ(sA6 - (float)hhA.h2[3][0], sA7 - (float)hhA.h2[3][1]);
        // stream B
        float sB0 = fmaxf(aB0.x + b0.x, 0.f);
        float sB1 = fmaxf(aB0.y + b0.y, 0.f);
        float sB2 = fmaxf(aB0.z + b0.z, 0.f);
        float sB3 = fmaxf(aB0.w + b0.w, 0.f);
        float sB4 = fmaxf(aB1.x + b1.x, 0.f);
        float sB5 = fmaxf(aB1.y + b1.y, 0.f);
        float sB6 = fmaxf(aB1.z + b1.z, 0.f);
        float sB7 = fmaxf(aB1.w + b1.w, 0.f);
        H8u hhB, hlB;
        hhB.h2[0] = PKRTZ(sB0, sB1);
        hhB.h2[1] = PKRTZ(sB2, sB3);
        hhB.h2[2] = PKRTZ(sB4, sB5);
        hhB.h2[3] = PKRTZ(sB6, sB7);
        hlB.h2[0] = PKRTZ(sB0 - (float)hhB.h2[0][0], sB1 - (float)hhB.h2[0][1]);
        hlB.h2[1] = PKRTZ(sB2 - (float)hhB.h2[1][0], sB3 - (float)hhB.h2[1][1]);
        hlB.h2[2] = PKRTZ(sB4 - (float)hhB.h2[2][0], sB5 - (float)hhB.h2[2][1]);
        hlB.h2[3] = PKRTZ(sB6 - (float)hhB.h2[3][0], sB7 - (float)hhB.h2[3][1]);
        #pragma unroll
        for (int nt = 0; nt < 4; ++nt) {
          accA[js][nt] = __builtin_amdgcn_mfma_f32_16x16x32_f16(hhA.h8, wh[nt], accA[js][nt], 0, 0, 0);
          accA[js][nt] = __builtin_amdgcn_mfma_f32_16x16x32_f16(hhA.h8, wl[nt], accA[js][nt], 0, 0, 0);
          accA[js][nt] = __builtin_amdgcn_mfma_f32_16x16x32_f16(hlA.h8, wh[nt], accA[js][nt], 0, 0, 0);
          accB[js][nt] = __builtin_amdgcn_mfma_f32_16x16x32_f16(hhB.h8, wh[nt], accB[js][nt], 0, 0, 0);
          accB[js][nt] = __builtin_amdgcn_mfma_f32_16x16x32_f16(hhB.h8, wl[nt], accB[js][nt], 0, 0, 0);
          accB[js][nt] = __builtin_amdgcn_mfma_f32_16x16x32_f16(hlB.h8, wh[nt], accB[js][nt], 0, 0, 0);
        }
      }
    }
#define EPILOG(ACC, IVAR)                                                     \
    _Pragma("unroll")                                                         \
    for (int js = 0; js < 4; ++js) {                                          \
      float p0 = 0.f, p1 = 0.f, p2 = 0.f, p3 = 0.f;                           \
      _Pragma("unroll")                                                       \
      for (int nt = 0; nt < 4; ++nt) {                                        \
        f32x4 v = ACC[js][nt];                                                \
        p0 += fmaxf(v[0], 0.f) * w3[nt];                                      \
        p1 += fmaxf(v[1], 0.f) * w3[nt];                                      \
        p2 += fmaxf(v[2], 0.f) * w3[nt];                                      \
        p3 += fmaxf(v[3], 0.f) * w3[nt];                                      \
      }                                                                       \
      _Pragma("unroll")                                                       \
      for (int m = 1; m <= 8; m <<= 1) {                                      \
        p0 += __shfl_xor(p0, m, 64);                                          \
        p1 += __shfl_xor(p1, m, 64);                                          \
        p2 += __shfl_xor(p2, m, 64);                                          \
        p3 += __shfl_xor(p3, m, 64);                                          \
      }                                                                       \
      if (r == 0) {                                                           \
        int jb2 = j0 + js * 16 + 4 * g;                                       \
        int i = IVAR;                                                         \
        int j; float logit;                                                   \
        j = jb2 + 0;                                                          \
        if (j > i) {                                                          \
          logit = p0 * INV_SH + be3v;                                         \
          out[i * (NN - 1) - (i * (i - 1)) / 2 + (j - i - 1)] =               \
              1.0f / (1.0f + expf(-logit));                                   \
        }                                                                     \
        j = jb2 + 1;                                                          \
        if (j > i) {                                                          \
          logit = p1 * INV_SH + be3v;                                         \
          out[i * (NN - 1) - (i * (i - 1)) / 2 + (j - i - 1)] =               \
              1.0f / (1.0f + expf(-logit));                                   \
        }                                                                     \
        j = jb2 + 2;                                                          \
        if (j > i) {                                                          \
          logit = p2 * INV_SH + be3v;                                         \
          out[i * (NN - 1) - (i * (i - 1)) / 2 + (j - i - 1)] =               \
              1.0f / (1.0f + expf(-logit));                                   \
        }                                                                     \
        j = jb2 + 3;                                                          \
        if (j > i) {                                                          \
          logit = p3 * INV_SH + be3v;                                         \
          out[i * (NN - 1) - (i * (i - 1)) / 2 + (j - i - 1)] =               \
              1.0f / (1.0f + expf(-logit));                                   \
        }                                                                     \
      }                                                                       \
    }
    EPILOG(accA, iA)
    EPILOG(accB, iB)
#undef EPILOG
  }
}

extern "C" void kernel_launch(void* const* d_in, const int* in_sizes, int n_in,
                              void* d_out, int out_size, void* d_ws, size_t ws_size,
                              hipStream_t stream) {
  (void)in_sizes; (void)n_in; (void)out_size; (void)ws_size;
  const float* nf  = (const float*)d_in[0];
  const float* adj = (const float*)d_in[1];
  const float* W0  = (const float*)d_in[2];
  const float* b0  = (const float*)d_in[3];
  const float* W1  = (const float*)d_in[4];
  const float* b1  = (const float*)d_in[5];
  const float* W2  = (const float*)d_in[6];
  const float* b2  = (const float*)d_in[7];
  const float* We1 = (const float*)d_in[8];
  const float* be1 = (const float*)d_in[9];
  const float* We2 = (const float*)d_in[10];
  const float* be2 = (const float*)d_in[11];
  const float* We3 = (const float*)d_in[12];
  const float* be3 = (const float*)d_in[13];
  float* out = (float*)d_out;

  // Workspace layout (max 3584 KB):
  //  [0,512K):    x0, later overwritten by x2 (x0 dead after layer 1)
  //  [512K,1024K): x1
  //  [1024K,1040K): Whg ; [1040K,1056K): Wlg
  //  [1536K,2560K): Ab ; [2560K,3584K): Bb
  char* ws = (char*)d_ws;
  float* x0 = (float*)(ws);
  float* x1 = (float*)(ws + (512 << 10));
  float* x2 = (float*)(ws);                        // reuse x0 slot
  _Float16* Whg = (_Float16*)(ws + (1024 << 10));  // 16 KB
  _Float16* Wlg = (_Float16*)(ws + (1040 << 10));  // 16 KB
  float* Ab = (float*)(ws + (1536 << 10));         // 1 MB (pre-scaled)
  float* Bb = (float*)(ws + (2560 << 10));         // 1 MB (pre-scaled)

  wsplit_kernel<<<32, 256, 0, stream>>>(We2, Whg, Wlg);
  gcn0_kernel<<<NN / 4, 256, 0, stream>>>(adj, nf, W0, b0, x0);
  gcnL_kernel<<<NN / 4, 256, 0, stream>>>(adj, x0, W1, b1, x1,
                                          nullptr, nullptr, nullptr, nullptr);
  gcnL_kernel<<<NN / 4, 256, 0, stream>>>(adj, x1, W2, b2, x2,
                                          We1, be1, Ab, Bb);
  pair_kernel<<<dim3(NN / 64, NN / 32), 512, 0, stream>>>(Ab, Bb, Whg, Wlg,
                                                          be2, We3, be3, out);
}

// Round 11
// 388.643 us; speedup vs baseline: 1.2672x; 1.0052x over previous
//
#include <hip/hip_runtime.h>
#include <math.h>

#define NN 2048
#define HH 64

typedef _Float16 half8 __attribute__((ext_vector_type(8)));
typedef _Float16 half2_t __attribute__((ext_vector_type(2)));
typedef float f32x4 __attribute__((ext_vector_type(4)));

#define SH (1.0f / 256.0f)
#define INV_SH 256.0f
#define BPAD 132  // f32 row stride

#if defined(__has_builtin)
#if __has_builtin(__builtin_amdgcn_cvt_pkrtz)
#define PKRTZ(a, b) ((half2_t)__builtin_amdgcn_cvt_pkrtz((a), (b)))
#endif
#endif
#ifndef PKRTZ
#define PKRTZ(a, b) ((half2_t){(_Float16)(a), (_Float16)(b)})
#endif

union H8u { half2_t h2[4]; half8 h8; };

// ---------- layer 0: x0 = relu((adj @ nf) @ W0 + b0), nf is (N,4) ----------
__global__ __launch_bounds__(256) void gcn0_kernel(const float* __restrict__ adj,
                                                   const float* __restrict__ nf,
                                                   const float* __restrict__ W0,
                                                   const float* __restrict__ b0,
                                                   float* __restrict__ xout) {
  int w = threadIdx.x >> 6;
  int l = threadIdx.x & 63;
  int i = blockIdx.x * 4 + w;
  const float* arow = adj + (size_t)i * NN;
  double s0 = 0, s1 = 0, s2 = 0, s3 = 0;
  for (int k = l; k < NN; k += 64) {
    float a = arow[k];
    float4 v = *(const float4*)(nf + (size_t)k * 4);
    s0 += (double)a * (double)v.x;
    s1 += (double)a * (double)v.y;
    s2 += (double)a * (double)v.z;
    s3 += (double)a * (double)v.w;
  }
  #pragma unroll
  for (int m = 32; m >= 1; m >>= 1) {
    s0 += __shfl_xor(s0, m, 64);
    s1 += __shfl_xor(s1, m, 64);
    s2 += __shfl_xor(s2, m, 64);
    s3 += __shfl_xor(s3, m, 64);
  }
  double y = (double)b0[l];
  y += s0 * (double)W0[0 * HH + l];
  y += s1 * (double)W0[1 * HH + l];
  y += s2 * (double)W0[2 * HH + l];
  y += s3 * (double)W0[3 * HH + l];
  float r = (float)y;
  xout[(size_t)i * HH + l] = r > 0.f ? r : 0.f;
}

// ---------- layers 1,2: xout = relu((adj @ xin) @ W + b); layer2 fuses A/B ----------
#define KT 128
__global__ __launch_bounds__(256) void gcnL_kernel(const float* __restrict__ adj,
                                                   const float* __restrict__ xin,
                                                   const float* __restrict__ W,
                                                   const float* __restrict__ b,
                                                   float* __restrict__ xout,
                                                   const float* __restrict__ We1,
                                                   const float* __restrict__ be1,
                                                   float* __restrict__ Aout,
                                                   float* __restrict__ Bout) {
  __shared__ float xs[KT][HH];
  __shared__ float adjs[4][KT];
  __shared__ double sred[4][HH];
  __shared__ float xr2[4][HH];
  int tid = threadIdx.x;
  int w = tid >> 6, l = tid & 63;
  int i0 = blockIdx.x * 4;
  double a0 = 0.0, a1 = 0.0, a2 = 0.0, a3 = 0.0;
  for (int k0 = 0; k0 < NN; k0 += KT) {
    __syncthreads();
    const float4* xsrc = (const float4*)(xin + (size_t)k0 * HH);
    float4* xdst = (float4*)&xs[0][0];
    for (int idx = tid; idx < KT * HH / 4; idx += 256) xdst[idx] = xsrc[idx];
    for (int idx = tid; idx < 4 * KT / 4; idx += 256) {
      int r = idx >> 5, c4 = idx & 31;
      *(float4*)&adjs[r][c4 * 4] =
          *(const float4*)(adj + (size_t)(i0 + r) * NN + k0 + c4 * 4);
    }
    __syncthreads();
    #pragma unroll 8
    for (int kk = 0; kk < KT; kk += 4) {
      float4 av = *(const float4*)&adjs[w][kk];   // wave-uniform b128 broadcast
      a0 += (double)av.x * (double)xs[kk + 0][l];
      a1 += (double)av.y * (double)xs[kk + 1][l];
      a2 += (double)av.z * (double)xs[kk + 2][l];
      a3 += (double)av.w * (double)xs[kk + 3][l];
    }
  }
  sred[w][l] = (a0 + a1) + (a2 + a3);
  __syncthreads();
  double y = (double)b[l];
  #pragma unroll 8
  for (int d = 0; d < HH; ++d) y += sred[w][d] * (double)W[d * HH + l];
  float r = (float)y;
  float rres = r > 0.f ? r : 0.f;
  xout[(size_t)(i0 + w) * HH + l] = rres;
  if (Aout != nullptr) {
    xr2[w][l] = rres;
    __syncthreads();
    #pragma unroll
    for (int t = 0; t < 2; ++t) {
      int idx = tid + t * 256;         // 0..511
      int rr = idx >> 7, c = idx & 127;
      const float* xr = xr2[rr];
      float accA = be1[c], accB = 0.f;
      #pragma unroll 8
      for (int d = 0; d < HH; ++d) {
        float xv = xr[d];
        accA = fmaf(xv, We1[d * 128 + c], accA);
        accB = fmaf(xv, We1[(HH + d) * 128 + c], accB);
      }
      Aout[(size_t)(i0 + rr) * 128 + c] = accA * SH;
      Bout[(size_t)(i0 + rr) * 128 + c] = accB * SH;
    }
  }
}

// ---------- one-shot We2 split: Wh/Wl f16 [c2][k] row-major ----------
__global__ __launch_bounds__(256) void wsplit_kernel(const float* __restrict__ We2,
                                                     _Float16* __restrict__ Whg,
                                                     _Float16* __restrict__ Wlg) {
  int idx = blockIdx.x * 256 + threadIdx.x;   // 0..8191
  int k = idx >> 6, c2 = idx & 63;
  float wv = We2[idx];
  _Float16 hi = (_Float16)wv;
  float lo = wv - (float)hi;
  Whg[c2 * 128 + k] = hi;
  Wlg[c2 * 128 + k] = (_Float16)lo;
}

// ---------- pair MLP via MFMA (split-f16), 16i x 64j tile, 4 waves ----------
// v6: explicitly software-pipelined ks-loop. cur/next register double-buffer
// for W (LDS, swizzled), B (LDS), A (GLOBAL - wave-uniform row, 1 line/load;
// As dropped from LDS entirely -> 66 KB, 2 blocks/CU). All prefetch vars have
// static indices (rule #20). Register budget ~248 <= 256 (launch_bounds(256,2)).
__global__ __launch_bounds__(256, 2) void pair_kernel(const float* __restrict__ A,
                                                      const float* __restrict__ B,
                                                      const _Float16* __restrict__ Whg,
                                                      const _Float16* __restrict__ Wlg,
                                                      const float* __restrict__ be2,
                                                      const float* __restrict__ We3,
                                                      const float* __restrict__ be3,
                                                      float* __restrict__ out) {
  int j0 = blockIdx.x * 64;
  int i0 = blockIdx.y * 16;
  if (i0 >= j0 + 63) return;         // no pair (i<j) in tile
  __shared__ __align__(16) _Float16 Wst8[2048 * 8];  // 32 KB, [Wh|Wl] swizzled
  __shared__ float Bs[64][BPAD];     // 33.8 KB
  __shared__ float be2s[64];
  __shared__ float We3s[64];
  int tid = threadIdx.x;
  int w = tid >> 6, l = tid & 63;
  int r = l & 15, g = l >> 4;

  {
    half8* Wst = (half8*)Wst8;
    #pragma unroll
    for (int t = 0; t < 8; ++t) {
      int idx = tid + t * 256;       // 0..2047
      int arr = idx >> 10;           // 0 = Wh, 1 = Wl
      int c = idx & 1023;
      int row = c >> 4, ch = c & 15;
      const half8* src = arr ? (const half8*)Wlg : (const half8*)Whg;
      Wst[arr * 1024 + row * 16 + (ch ^ (row & 15))] = src[c];
    }
  }
  #pragma unroll
  for (int t = 0; t < 8; ++t) {
    int idx = tid + t * 256;         // 0..2047
    int rr = idx >> 5, c4 = idx & 31;
    *(float4*)&Bs[rr][c4 * 4] = *(const float4*)(B + (size_t)(j0 + rr) * 128 + c4 * 4);
  }
  if (tid < 64) { be2s[tid] = be2[tid]; We3s[tid] = We3[tid]; }
  __syncthreads();

  const half8* Wst = (const half8*)Wst8;
  float be3v = be3[0];
  float w3[4], sb[4];
  #pragma unroll
  for (int nt = 0; nt < 4; ++nt) {
    w3[nt] = We3s[nt * 16 + r];
    sb[nt] = SH * be2s[nt * 16 + r];
  }

  #pragma unroll 1
  for (int p = 0; p < 4; ++p) {
    int ir = w * 4 + p;              // wave-uniform
    int i = i0 + ir;
    if (i >= j0 + 63) continue;
    const float* Arow = A + (size_t)i * 128;

    // ---- pipeline prologue: load ks=0 ----
    float4 a0c, a1c, a0n, a1n;
    half8 whc[4], wlc[4], whn[4], wln[4];
    float4 b0c[4], b1c[4], b0n[4], b1n[4];
    a0c = *(const float4*)(Arow + 8 * g);
    a1c = *(const float4*)(Arow + 8 * g + 4);
    #pragma unroll
    for (int nt = 0; nt < 4; ++nt) {
      int a = (nt * 16 + r) * 16 + (g ^ r);
      whc[nt] = Wst[a];
      wlc[nt] = Wst[1024 + a];
    }
    #pragma unroll
    for (int js = 0; js < 4; ++js) {
      b0c[js] = *(const float4*)&Bs[js * 16 + r][8 * g];
      b1c[js] = *(const float4*)&Bs[js * 16 + r][8 * g + 4];
    }

    f32x4 acc[4][4];
    #pragma unroll
    for (int js = 0; js < 4; ++js) {
      #pragma unroll
      for (int nt = 0; nt < 4; ++nt) {
        acc[js][nt][0] = sb[nt]; acc[js][nt][1] = sb[nt];
        acc[js][nt][2] = sb[nt]; acc[js][nt][3] = sb[nt];
      }
    }

    #pragma unroll
    for (int ks = 0; ks < 4; ++ks) {
      // ---- prefetch ks+1 into 'next' regs (issued before the compute) ----
      if (ks < 3) {
        int kb2 = (ks + 1) * 32 + 8 * g;
        a0n = *(const float4*)(Arow + kb2);
        a1n = *(const float4*)(Arow + kb2 + 4);
        #pragma unroll
        for (int nt = 0; nt < 4; ++nt) {
          int a = (nt * 16 + r) * 16 + (((ks + 1) * 4 + g) ^ r);
          whn[nt] = Wst[a];
          wln[nt] = Wst[1024 + a];
        }
        #pragma unroll
        for (int js = 0; js < 4; ++js) {
          b0n[js] = *(const float4*)&Bs[js * 16 + r][kb2];
          b1n[js] = *(const float4*)&Bs[js * 16 + r][kb2 + 4];
        }
      }
      // ---- compute current ks ----
      #pragma unroll
      for (int js = 0; js < 4; ++js) {
        float s0 = fmaxf(a0c.x + b0c[js].x, 0.f);
        float s1 = fmaxf(a0c.y + b0c[js].y, 0.f);
        float s2 = fmaxf(a0c.z + b0c[js].z, 0.f);
        float s3 = fmaxf(a0c.w + b0c[js].w, 0.f);
        float s4 = fmaxf(a1c.x + b1c[js].x, 0.f);
        float s5 = fmaxf(a1c.y + b1c[js].y, 0.f);
        float s6 = fmaxf(a1c.z + b1c[js].z, 0.f);
        float s7 = fmaxf(a1c.w + b1c[js].w, 0.f);
        H8u hh, hl;
        hh.h2[0] = PKRTZ(s0, s1);
        hh.h2[1] = PKRTZ(s2, s3);
        hh.h2[2] = PKRTZ(s4, s5);
        hh.h2[3] = PKRTZ(s6, s7);
        hl.h2[0] = PKRTZ(s0 - (float)hh.h2[0][0], s1 - (float)hh.h2[0][1]);
        hl.h2[1] = PKRTZ(s2 - (float)hh.h2[1][0], s3 - (float)hh.h2[1][1]);
        hl.h2[2] = PKRTZ(s4 - (float)hh.h2[2][0], s5 - (float)hh.h2[2][1]);
        hl.h2[3] = PKRTZ(s6 - (float)hh.h2[3][0], s7 - (float)hh.h2[3][1]);
        #pragma unroll
        for (int nt = 0; nt < 4; ++nt) {
          acc[js][nt] = __builtin_amdgcn_mfma_f32_16x16x32_f16(hh.h8, whc[nt], acc[js][nt], 0, 0, 0);
          acc[js][nt] = __builtin_amdgcn_mfma_f32_16x16x32_f16(hh.h8, wlc[nt], acc[js][nt], 0, 0, 0);
          acc[js][nt] = __builtin_amdgcn_mfma_f32_16x16x32_f16(hl.h8, whc[nt], acc[js][nt], 0, 0, 0);
        }
      }
      // ---- rotate buffers ----
      if (ks < 3) {
        a0c = a0n; a1c = a1n;
        #pragma unroll
        for (int nt = 0; nt < 4; ++nt) { whc[nt] = whn[nt]; wlc[nt] = wln[nt]; }
        #pragma unroll
        for (int js = 0; js < 4; ++js) { b0c[js] = b0n[js]; b1c[js] = b1n[js]; }
      }
    }

    // epilogue: h2 = relu(acc)/SH; logit = sum h2*We3 + be3
    #pragma unroll
    for (int js = 0; js < 4; ++js) {
      float p0 = 0.f, p1 = 0.f, p2 = 0.f, p3 = 0.f;
      #pragma unroll
      for (int nt = 0; nt < 4; ++nt) {
        f32x4 v = acc[js][nt];
        p0 += fmaxf(v[0], 0.f) * w3[nt];
        p1 += fmaxf(v[1], 0.f) * w3[nt];
        p2 += fmaxf(v[2], 0.f) * w3[nt];
        p3 += fmaxf(v[3], 0.f) * w3[nt];
      }
      #pragma unroll
      for (int m = 1; m <= 8; m <<= 1) {
        p0 += __shfl_xor(p0, m, 64);
        p1 += __shfl_xor(p1, m, 64);
        p2 += __shfl_xor(p2, m, 64);
        p3 += __shfl_xor(p3, m, 64);
      }
      if (r == 0) {
        int jb2 = j0 + js * 16 + 4 * g;
        int j;
        float logit;
        j = jb2 + 0;
        if (j > i) {
          logit = p0 * INV_SH + be3v;
          out[i * (NN - 1) - (i * (i - 1)) / 2 + (j - i - 1)] =
              1.0f / (1.0f + expf(-logit));
        }
        j = jb2 + 1;
        if (j > i) {
          logit = p1 * INV_SH + be3v;
          out[i * (NN - 1) - (i * (i - 1)) / 2 + (j - i - 1)] =
              1.0f / (1.0f + expf(-logit));
        }
        j = jb2 + 2;
        if (j > i) {
          logit = p2 * INV_SH + be3v;
          out[i * (NN - 1) - (i * (i - 1)) / 2 + (j - i - 1)] =
              1.0f / (1.0f + expf(-logit));
        }
        j = jb2 + 3;
        if (j > i) {
          logit = p3 * INV_SH + be3v;
          out[i * (NN - 1) - (i * (i - 1)) / 2 + (j - i - 1)] =
              1.0f / (1.0f + expf(-logit));
        }
      }
    }
  }
}

extern "C" void kernel_launch(void* const* d_in, const int* in_sizes, int n_in,
                              void* d_out, int out_size, void* d_ws, size_t ws_size,
                              hipStream_t stream) {
  (void)in_sizes; (void)n_in; (void)out_size; (void)ws_size;
  const float* nf  = (const float*)d_in[0];
  const float* adj = (const float*)d_in[1];
  const float* W0  = (const float*)d_in[2];
  const float* b0  = (const float*)d_in[3];
  const float* W1  = (const float*)d_in[4];
  const float* b1  = (const float*)d_in[5];
  const float* W2  = (const float*)d_in[6];
  const float* b2  = (const float*)d_in[7];
  const float* We1 = (const float*)d_in[8];
  const float* be1 = (const float*)d_in[9];
  const float* We2 = (const float*)d_in[10];
  const float* be2 = (const float*)d_in[11];
  const float* We3 = (const float*)d_in[12];
  const float* be3 = (const float*)d_in[13];
  float* out = (float*)d_out;

  // Workspace layout (max 3584 KB):
  //  [0,512K):    x0, later overwritten by x2 (x0 dead after layer 1)
  //  [512K,1024K): x1
  //  [1024K,1040K): Whg ; [1040K,1056K): Wlg
  //  [1536K,2560K): Ab ; [2560K,3584K): Bb
  char* ws = (char*)d_ws;
  float* x0 = (float*)(ws);
  float* x1 = (float*)(ws + (512 << 10));
  float* x2 = (float*)(ws);                        // reuse x0 slot
  _Float16* Whg = (_Float16*)(ws + (1024 << 10));  // 16 KB
  _Float16* Wlg = (_Float16*)(ws + (1040 << 10));  // 16 KB
  float* Ab = (float*)(ws + (1536 << 10));         // 1 MB (pre-scaled)
  float* Bb = (float*)(ws + (2560 << 10));         // 1 MB (pre-scaled)

  wsplit_kernel<<<32, 256, 0, stream>>>(We2, Whg, Wlg);
  gcn0_kernel<<<NN / 4, 256, 0, stream>>>(adj, nf, W0, b0, x0);
  gcnL_kernel<<<NN / 4, 256, 0, stream>>>(adj, x0, W1, b1, x1,
                                          nullptr, nullptr, nullptr, nullptr);
  gcnL_kernel<<<NN / 4, 256, 0, stream>>>(adj, x1, W2, b2, x2,
                                          We1, be1, Ab, Bb);
  pair_kernel<<<dim3(NN / 64, NN / 16), 256, 0, stream>>>(Ab, Bb, Whg, Wlg,
                                                          be2, We3, be3, out);
}